// Round 3
// baseline (184.176 us; speedup 1.0000x reference)
//
#include <hip/hip_runtime.h>
#include <math.h>

#define VOCAB 2048
#define TPB   256
#define NBINS 64
// 64 bins cover (m - v) in [0, 64/6 = 10.667); kept tokens provably have
// m - v <= ln(2048/0.05) = 10.62, so the top-p crossing is always inside,
// and the mass beyond bin 63 is <= 2048*e^-10.667 <= 0.048 <= 0.05*S (S>=1),
// so the ballot below always finds a boundary bin.
#define BIN_SCALE 6.0f
#define BCAP  512   // boundary-bin candidate cap (~6 expected)
#define KCAP  512   // kept-token cap (overflow -> inline gumbel fallback)

typedef float vf4 __attribute__((ext_vector_type(4)));

__device__ __forceinline__ unsigned long long pack_key(float z, int idx) {
    unsigned zb = __float_as_uint(z);
    zb = (zb & 0x80000000u) ? ~zb : (zb | 0x80000000u);       // order-preserving
    return ((unsigned long long)zb << 32) | (unsigned)(VOCAB - 1 - idx); // min-idx tiebreak
}

__global__ __launch_bounds__(TPB, 8) void sampler_kernel(
    const float* __restrict__ logits,
    const float* __restrict__ uni,
    float* __restrict__ out_idx,    // [B]   sampled index as float
    float* __restrict__ out_probs)  // [B,V] filtered softmax
{
    const int row  = blockIdx.x;
    const int t    = threadIdx.x;
    const int lane = t & 63;
    const int wid  = t >> 6;

    __shared__ float  s_bins[NBINS];
    __shared__ float  s_wf[4];
    __shared__ double s_wd[4];
    __shared__ unsigned long long s_key[4];
    __shared__ int    s_cnt, s_cnt2;
    __shared__ float  s_cv[BCAP];   // boundary-bin candidate values
    __shared__ float  s_ce[BCAP];   // boundary-bin candidate exps
    __shared__ float  s_kv[KCAP];   // kept: scaled logit
    __shared__ float  s_ku[KCAP];   // kept: uniform noise (from registers!)
    __shared__ int    s_ki[KCAP];   // kept: index

    const float* lrow = logits    + (size_t)row * VOCAB;
    const float* urow = uni       + (size_t)row * VOCAB;
    float*       prow = out_probs + (size_t)row * VOCAB;

    if (t < NBINS) s_bins[t] = 0.0f;
    if (t == 0) { s_cnt = 0; s_cnt2 = 0; }

    // ---- all 4 global vector loads issued up front (deep MLP) ----
    const vf4 a0 = *(const vf4*)(lrow + 4 * t);
    const vf4 a1 = *(const vf4*)(lrow + VOCAB / 2 + 4 * t);
    const vf4 u0 = *(const vf4*)(urow + 4 * t);
    const vf4 u1 = *(const vf4*)(urow + VOCAB / 2 + 4 * t);
    float s[8]  = {a0.x * 1.25f, a0.y * 1.25f, a0.z * 1.25f, a0.w * 1.25f,
                   a1.x * 1.25f, a1.y * 1.25f, a1.z * 1.25f, a1.w * 1.25f};
    float uu[8] = {u0.x, u0.y, u0.z, u0.w, u1.x, u1.y, u1.z, u1.w};

    // ---- block max ----
    float lm = s[0];
    #pragma unroll
    for (int j = 1; j < 8; j++) lm = fmaxf(lm, s[j]);
    #pragma unroll
    for (int off = 32; off; off >>= 1) lm = fmaxf(lm, __shfl_down(lm, off));
    if (lane == 0) s_wf[wid] = lm;
    __syncthreads();                                    // B1 (covers LDS init too)
    const float m = fmaxf(fmaxf(s_wf[0], s_wf[1]), fmaxf(s_wf[2], s_wf[3]));

    // ---- exp, total sum (double), exp-mass histogram ----
    float e[8];
    float psum = 0.0f;
    #pragma unroll
    for (int j = 0; j < 8; j++) {
        e[j] = __expf(s[j] - m);
        psum += e[j];
        int b = (int)((m - s[j]) * BIN_SCALE);
        if (b < NBINS) atomicAdd(&s_bins[b], e[j]);
    }
    double dp = (double)psum;
    #pragma unroll
    for (int off = 32; off; off >>= 1) dp += __shfl_down(dp, off);
    if (lane == 0) s_wd[wid] = dp;
    __syncthreads();                                    // B2

    // ---- replicated in every wave: S, 64-bin prefix scan, boundary bin ----
    const double S  = s_wd[0] + s_wd[1] + s_wd[2] + s_wd[3];
    const double pS = 0.95 * S;
    const float  bf = s_bins[lane];
    double c = (double)bf;
    #pragma unroll
    for (int d = 1; d < 64; d <<= 1) {
        double o = __shfl_up(c, d);
        if (lane >= d) c += o;
    }
    unsigned long long ball = __ballot(c > pS);
    const int    bstar     = ball ? (__ffsll(ball) - 1) : (NBINS - 1);
    const double cumBefore = __shfl(c - (double)bf, bstar);   // exclusive prefix

    // ---- compact boundary-bin candidates ----
    #pragma unroll
    for (int j = 0; j < 8; j++) {
        int b = (int)((m - s[j]) * BIN_SCALE);
        if (b == bstar) {
            int pos = atomicAdd(&s_cnt, 1);
            if (pos < BCAP) { s_cv[pos] = s[j]; s_ce[pos] = e[j]; }
        }
    }
    __syncthreads();                                    // B3
    const int cnt = min(s_cnt, BCAP);

    // ---- replicated O(cnt^2) boundary resolution -> SK (no reduction barrier) ----
    float SKb = 0.0f;
    for (int i = 0; i < cnt; i++) {
        float vi = s_cv[i], part = 0.0f;
        for (int jj = 0; jj < cnt; jj++)
            part += (s_cv[jj] > vi) ? s_ce[jj] : 0.0f;  // broadcast reads
        if (cumBefore + (double)part <= pS) SKb += s_ce[i];
    }
    const float invSK = 1.0f / (float)(cumBefore + (double)SKb);

    // ---- per-element keep decision ----
    unsigned keptMask = 0;
    #pragma unroll
    for (int j = 0; j < 8; j++) {
        int  b = (int)((m - s[j]) * BIN_SCALE);
        bool kept;
        if (b < bstar)      kept = true;
        else if (b > bstar) kept = false;
        else {
            float part = 0.0f;
            for (int i = 0; i < cnt; i++)
                part += (s_cv[i] > s[j]) ? s_ce[i] : 0.0f;
            kept = (cumBefore + (double)part) <= pS;
        }
        if (kept) keptMask |= (1u << j);
    }

    // ---- write probs (nontemporal; never re-read) ----
    vf4 p0, p1;
    p0.x = (keptMask & 0x01) ? e[0] * invSK : 0.0f;
    p0.y = (keptMask & 0x02) ? e[1] * invSK : 0.0f;
    p0.z = (keptMask & 0x04) ? e[2] * invSK : 0.0f;
    p0.w = (keptMask & 0x08) ? e[3] * invSK : 0.0f;
    p1.x = (keptMask & 0x10) ? e[4] * invSK : 0.0f;
    p1.y = (keptMask & 0x20) ? e[5] * invSK : 0.0f;
    p1.z = (keptMask & 0x40) ? e[6] * invSK : 0.0f;
    p1.w = (keptMask & 0x80) ? e[7] * invSK : 0.0f;
    __builtin_nontemporal_store(p0, (vf4*)(prow + 4 * t));
    __builtin_nontemporal_store(p1, (vf4*)(prow + VOCAB / 2 + 4 * t));

    // ---- compact kept tokens (value, u, idx) from REGISTERS ----
    unsigned long long ovKey = 0ull;
    #pragma unroll
    for (int j = 0; j < 8; j++) {
        if ((keptMask >> j) & 1u) {
            int idx = (j < 4) ? (4 * t + j) : (VOCAB / 2 + 4 * t + (j - 4));
            int pos = atomicAdd(&s_cnt2, 1);
            if (pos < KCAP) { s_kv[pos] = s[j]; s_ku[pos] = uu[j]; s_ki[pos] = idx; }
            else {          // overflow fallback: inline gumbel (rare/never)
                float z = s[j] + (-logf(-logf(uu[j])));
                unsigned long long kk = pack_key(z, idx);
                ovKey = (kk > ovKey) ? kk : ovKey;
            }
        }
    }
    __syncthreads();                                    // B4
    const int k  = s_cnt2;
    const int kl = min(k, KCAP);

    // ---- Gumbel-max over kept tokens (precise lib logf, from LDS) ----
    unsigned long long key = ovKey;
    for (int i = t; i < kl; i += TPB) {
        float z = s_kv[i] + (-logf(-logf(s_ku[i])));
        unsigned long long kk = pack_key(z, s_ki[i]);
        key = (kk > key) ? kk : key;
    }

    if (k <= 64) {
        // all entries live in wave 0: wave-local reduce, no barrier
        if (wid == 0) {
            #pragma unroll
            for (int off = 32; off; off >>= 1) {
                unsigned long long ok = __shfl_down(key, off);
                key = (ok > key) ? ok : key;
            }
            if (lane == 0)
                out_idx[row] = (float)(VOCAB - 1 - (int)(key & 0xFFFFFFFFu));
        }
    } else {
        #pragma unroll
        for (int off = 32; off; off >>= 1) {
            unsigned long long ok = __shfl_down(key, off);
            key = (ok > key) ? ok : key;
        }
        if (lane == 0) s_key[wid] = key;
        __syncthreads();                                // B5 (uncommon path)
        if (t == 0) {
            unsigned long long k0 = s_key[0];
            #pragma unroll
            for (int w = 1; w < 4; w++) k0 = (s_key[w] > k0) ? s_key[w] : k0;
            out_idx[row] = (float)(VOCAB - 1 - (int)(k0 & 0xFFFFFFFFu));
        }
    }
}

extern "C" void kernel_launch(void* const* d_in, const int* in_sizes, int n_in,
                              void* d_out, int out_size, void* d_ws, size_t ws_size,
                              hipStream_t stream) {
    const float* logits = (const float*)d_in[0];
    const float* u      = (const float*)d_in[1];
    const int B = in_sizes[0] / VOCAB;   // 8192
    float* out_idx   = (float*)d_out;          // sampled [B,1] flattened, in return order
    float* out_probs = (float*)d_out + B;      // probs [B,V]
    sampler_kernel<<<B, TPB, 0, stream>>>(logits, u, out_idx, out_probs);
}

// Round 4
// 183.770 us; speedup vs baseline: 1.0022x; 1.0022x over previous
//
#include <hip/hip_runtime.h>
#include <math.h>

#define VOCAB 2048
#define TPB   256
#define NBINS 64
// 64 bins cover (m - v) in [0, 64/6 = 10.667); kept tokens provably have
// m - v <= ln(2048/0.05) = 10.62, so the top-p crossing is always inside,
// and the mass beyond bin 63 is <= 2048*e^-10.667 <= 0.048 <= 0.05*S (S>=1),
// so the ballot below always finds a boundary bin (fallback 63 regardless).
#define BIN_SCALE 6.0f
#define BCAP  512   // boundary-bin candidate cap (~6 expected, 85x margin)

typedef float vf4 __attribute__((ext_vector_type(4)));

__device__ __forceinline__ unsigned long long pack_key(float z, int idx) {
    unsigned zb = __float_as_uint(z);
    zb = (zb & 0x80000000u) ? ~zb : (zb | 0x80000000u);       // order-preserving
    return ((unsigned long long)zb << 32) | (unsigned)(VOCAB - 1 - idx); // min-idx tiebreak
}

__global__ __launch_bounds__(TPB, 8) void sampler_kernel(
    const float* __restrict__ logits,
    const float* __restrict__ uni,
    float* __restrict__ out_idx,    // [B]   sampled index as float
    float* __restrict__ out_probs)  // [B,V] filtered softmax
{
    const int row  = blockIdx.x;
    const int t    = threadIdx.x;
    const int lane = t & 63;
    const int wid  = t >> 6;

    __shared__ float  s_bins[NBINS];
    __shared__ float  s_wf[4];
    __shared__ double s_wd[4];
    __shared__ unsigned long long s_key[4];
    __shared__ int    s_cnt;
    __shared__ float  s_cv[BCAP];   // boundary-bin candidate values
    __shared__ float  s_ce[BCAP];   // boundary-bin candidate exps

    const float* lrow = logits    + (size_t)row * VOCAB;
    const float* urow = uni       + (size_t)row * VOCAB;
    float*       prow = out_probs + (size_t)row * VOCAB;

    if (t < NBINS) s_bins[t] = 0.0f;
    if (t == 0) s_cnt = 0;

    // ---- load logits only (u is gathered sparsely at the end) ----
    const vf4 a0 = *(const vf4*)(lrow + 4 * t);
    const vf4 a1 = *(const vf4*)(lrow + VOCAB / 2 + 4 * t);
    float s[8] = {a0.x * 1.25f, a0.y * 1.25f, a0.z * 1.25f, a0.w * 1.25f,
                  a1.x * 1.25f, a1.y * 1.25f, a1.z * 1.25f, a1.w * 1.25f};

    // ---- block max ----
    float lm = s[0];
    #pragma unroll
    for (int j = 1; j < 8; j++) lm = fmaxf(lm, s[j]);
    #pragma unroll
    for (int off = 32; off; off >>= 1) lm = fmaxf(lm, __shfl_down(lm, off));
    if (lane == 0) s_wf[wid] = lm;
    __syncthreads();                                    // B1 (covers LDS init too)
    const float m = fmaxf(fmaxf(s_wf[0], s_wf[1]), fmaxf(s_wf[2], s_wf[3]));

    // ---- exp, total sum (double), exp-mass histogram ----
    float e[8];
    int   bin[8];
    float psum = 0.0f;
    #pragma unroll
    for (int j = 0; j < 8; j++) {
        e[j] = __expf(s[j] - m);
        psum += e[j];
        bin[j] = (int)((m - s[j]) * BIN_SCALE);
        if (bin[j] < NBINS) atomicAdd(&s_bins[bin[j]], e[j]);
    }
    double dp = (double)psum;
    #pragma unroll
    for (int off = 32; off; off >>= 1) dp += __shfl_down(dp, off);
    if (lane == 0) s_wd[wid] = dp;
    __syncthreads();                                    // B2

    // ---- replicated in every wave: S, 64-bin prefix scan, boundary bin ----
    const double S  = s_wd[0] + s_wd[1] + s_wd[2] + s_wd[3];
    const double pS = 0.95 * S;
    const float  bf = s_bins[lane];
    double c = (double)bf;
    #pragma unroll
    for (int d = 1; d < 64; d <<= 1) {
        double o = __shfl_up(c, d);
        if (lane >= d) c += o;
    }
    unsigned long long ball = __ballot(c > pS);
    const int    bstar     = ball ? (__ffsll(ball) - 1) : (NBINS - 1);
    const double cumBefore = __shfl(c - (double)bf, bstar);   // exclusive prefix

    // ---- compact boundary-bin candidates ----
    #pragma unroll
    for (int j = 0; j < 8; j++) {
        if (bin[j] == bstar) {
            int pos = atomicAdd(&s_cnt, 1);
            if (pos < BCAP) { s_cv[pos] = s[j]; s_ce[pos] = e[j]; }
        }
    }
    __syncthreads();                                    // B3
    const int cnt = min(s_cnt, BCAP);

    // ---- replicated O(cnt^2) boundary resolution -> SK (no reduction barrier) ----
    // kept mass below boundary bin == cumBefore (same f32-histogram values the
    // scan summed in f64), so SK = cumBefore + kept boundary mass.
    float SKb = 0.0f;
    for (int i = 0; i < cnt; i++) {
        float vi = s_cv[i], part = 0.0f;
        for (int jj = 0; jj < cnt; jj++)
            part += (s_cv[jj] > vi) ? s_ce[jj] : 0.0f;  // broadcast reads
        if (cumBefore + (double)part <= pS) SKb += s_ce[i];
    }
    const float invSK = 1.0f / (float)(cumBefore + (double)SKb);

    // ---- per-element keep decision ----
    unsigned keptMask = 0;
    #pragma unroll
    for (int j = 0; j < 8; j++) {
        bool kept;
        if (bin[j] < bstar)      kept = true;
        else if (bin[j] > bstar) kept = false;
        else {
            float part = 0.0f;
            for (int i = 0; i < cnt; i++)
                part += (s_cv[i] > s[j]) ? s_ce[i] : 0.0f;
            kept = (cumBefore + (double)part) <= pS;
        }
        if (kept) keptMask |= (1u << j);
    }

    // ---- write probs (nontemporal; never re-read) ----
    vf4 p0, p1;
    p0.x = (keptMask & 0x01) ? e[0] * invSK : 0.0f;
    p0.y = (keptMask & 0x02) ? e[1] * invSK : 0.0f;
    p0.z = (keptMask & 0x04) ? e[2] * invSK : 0.0f;
    p0.w = (keptMask & 0x08) ? e[3] * invSK : 0.0f;
    p1.x = (keptMask & 0x10) ? e[4] * invSK : 0.0f;
    p1.y = (keptMask & 0x20) ? e[5] * invSK : 0.0f;
    p1.z = (keptMask & 0x40) ? e[6] * invSK : 0.0f;
    p1.w = (keptMask & 0x80) ? e[7] * invSK : 0.0f;
    __builtin_nontemporal_store(p0, (vf4*)(prow + 4 * t));
    __builtin_nontemporal_store(p1, (vf4*)(prow + VOCAB / 2 + 4 * t));

    // ---- inline Gumbel for this thread's kept elements (sparse L3 gather) ----
    unsigned long long key = 0ull;
    #pragma unroll
    for (int j = 0; j < 8; j++) {
        if ((keptMask >> j) & 1u) {
            int   idx = (j < 4) ? (4 * t + j) : (VOCAB / 2 + 4 * t + (j - 4));
            float uv  = urow[idx];
            float z   = s[j] + (-logf(-logf(uv)));      // precise lib logf
            unsigned long long kk = pack_key(z, idx);
            key = (kk > key) ? kk : key;
        }
    }
    #pragma unroll
    for (int off = 32; off; off >>= 1) {
        unsigned long long ok = __shfl_down(key, off);
        key = (ok > key) ? ok : key;
    }
    if (lane == 0) s_key[wid] = key;
    __syncthreads();                                    // B4
    if (t == 0) {
        unsigned long long k0 = s_key[0];
        #pragma unroll
        for (int w = 1; w < 4; w++) k0 = (s_key[w] > k0) ? s_key[w] : k0;
        out_idx[row] = (float)(VOCAB - 1 - (int)(k0 & 0xFFFFFFFFu));
    }
}

extern "C" void kernel_launch(void* const* d_in, const int* in_sizes, int n_in,
                              void* d_out, int out_size, void* d_ws, size_t ws_size,
                              hipStream_t stream) {
    const float* logits = (const float*)d_in[0];
    const float* u      = (const float*)d_in[1];
    const int B = in_sizes[0] / VOCAB;   // 8192
    float* out_idx   = (float*)d_out;          // sampled [B,1] flattened, in return order
    float* out_probs = (float*)d_out + B;      // probs [B,V]
    sampler_kernel<<<B, TPB, 0, stream>>>(logits, u, out_idx, out_probs);
}